// Round 3
// baseline (361.055 us; speedup 1.0000x reference)
//
#include <hip/hip_runtime.h>
#include <stdint.h>

// ---------------- problem constants ----------------
#define B_BATCH 16
#define SEQ     2048
#define DIMD    128
#define QT_OUT  28            // output rows per tile
#define SROWS   30            // score rows kept in LDS (halo +1 each side)
#define TILES_PB 74           // ceil(2048/28)
#define SCALE   0.08838834764831845f   // 1/sqrt(128)
#define L2E     1.4426950408889634f

#define SC_STRIDE 4096                     // bytes per score row (2048 bf16)
#define STG_OFF   (SROWS * SC_STRIDE)      // 122880
#define LDS_TOTAL (STG_OFF + 2 * 16384)    // 155648 (<160 KiB)

typedef __attribute__((ext_vector_type(8))) short bf16x8;
typedef __attribute__((ext_vector_type(4))) float f32x4;

__device__ __forceinline__ unsigned short f2bf(float f) {
  union { float f; uint32_t u; } v; v.f = f;
  uint32_t u = v.u;
  return (unsigned short)((u + 0x7FFFu + ((u >> 16) & 1u)) >> 16);  // RNE
}
__device__ __forceinline__ float bf2f(unsigned short h) {
  union { uint32_t u; float f; } v; v.u = ((uint32_t)h) << 16;
  return v.f;
}
// async global->LDS, 16B per lane; LDS dest is wave-uniform base + lane*16
__device__ __forceinline__ void gll16(const void* g, void* l) {
  __builtin_amdgcn_global_load_lds(
      (const __attribute__((address_space(1))) unsigned int*)g,
      (__attribute__((address_space(3))) unsigned int*)l, 16, 0, 0);
}

// ---------------- prepass 1: K fp32 -> bf16 (row-major) ----------------
__global__ __launch_bounds__(256) void cvt_bf16(const float* __restrict__ in,
                                                unsigned short* __restrict__ out) {
  const size_t i = (size_t)blockIdx.x * 256 + threadIdx.x;   // 8 elems per thread
  const float4 a = *(const float4*)(in + i * 8);
  const float4 b = *(const float4*)(in + i * 8 + 4);
  uint4 o;
  o.x = (uint32_t)f2bf(a.x) | ((uint32_t)f2bf(a.y) << 16);
  o.y = (uint32_t)f2bf(a.z) | ((uint32_t)f2bf(a.w) << 16);
  o.z = (uint32_t)f2bf(b.x) | ((uint32_t)f2bf(b.y) << 16);
  o.w = (uint32_t)f2bf(b.z) | ((uint32_t)f2bf(b.w) << 16);
  *(uint4*)(out + i * 8) = o;
}

// ---------------- prepass 2: V -> V^T bf16 ([b][d][k]) ----------------
__global__ __launch_bounds__(256) void transpose_v(const float* __restrict__ V,
                                                   unsigned short* __restrict__ Vt) {
  __shared__ float tl[64][65];
  const int b  = blockIdx.x >> 6;
  const int kt = (blockIdx.x & 63) >> 1;
  const int dt = blockIdx.x & 1;
  const int k0 = kt * 64, d0 = dt * 64;
  const int tid = threadIdx.x;
  const int r = tid >> 4, c4 = (tid & 15) * 4;
  const float* Vb = V + (size_t)b * SEQ * DIMD;
#pragma unroll
  for (int ii = 0; ii < 4; ++ii) {
    const int row = ii * 16 + r;
    float4 v = *(const float4*)(Vb + (size_t)(k0 + row) * DIMD + d0 + c4);
    tl[row][c4 + 0] = v.x; tl[row][c4 + 1] = v.y;
    tl[row][c4 + 2] = v.z; tl[row][c4 + 3] = v.w;
  }
  __syncthreads();
  unsigned short* VtB = Vt + (size_t)b * DIMD * SEQ;
#pragma unroll
  for (int ii = 0; ii < 4; ++ii) {
    const int drow = ii * 16 + r;
    ushort4 o;
    o.x = f2bf(tl[c4 + 0][drow]); o.y = f2bf(tl[c4 + 1][drow]);
    o.z = f2bf(tl[c4 + 2][drow]); o.w = f2bf(tl[c4 + 3][drow]);
    *(ushort4*)(VtB + (size_t)(d0 + drow) * SEQ + k0 + c4) = o;
  }
}

// ---------------- fused: QK^T -> conv -> softmax -> (atten out, PV) ----------------
__global__ __launch_bounds__(512) void fused_attn(
    const float* __restrict__ Q, const unsigned short* __restrict__ Kb,
    const unsigned short* __restrict__ Vt, const int* __restrict__ msk,
    const float* __restrict__ cw, const float* __restrict__ cbv,
    float* __restrict__ ctx, float* __restrict__ attn) {
  __shared__ __align__(16) char smem[LDS_TOTAL];
  char* buf0 = smem + STG_OFF;
  char* buf1 = buf0 + 16384;

  const int bid = blockIdx.x;
  const int b  = bid / TILES_PB;
  const int t  = bid - b * TILES_PB;
  const int g0 = t * QT_OUT;
  const int tid = threadIdx.x;
  const int w = tid >> 6, lane = tid & 63, l15 = lane & 15, hi = lane >> 4;

  float w9[9];
#pragma unroll
  for (int i = 0; i < 9; ++i) w9[i] = cw[b * 9 + i];
  const float bias = cbv[b];

  // per-lane column mask bits (cols jb*256 + lane*4 + c -> bit jb*4+c)
  uint32_t mb = 0;
  {
    const int* mp = msk + b * SEQ;
#pragma unroll
    for (int jb = 0; jb < 8; ++jb) {
      int4 mv = *(const int4*)(mp + jb * 256 + lane * 4);
      mb |= (mv.x != 0 ? 1u : 0u) << (jb * 4 + 0);
      mb |= (mv.y != 0 ? 1u : 0u) << (jb * 4 + 1);
      mb |= (mv.z != 0 ? 1u : 0u) << (jb * 4 + 2);
      mb |= (mv.w != 0 ? 1u : 0u) << (jb * 4 + 3);
    }
  }

  // ---- Q fragments (A operand), fp32 global -> bf16 regs ----
  bf16x8 aq[2][4];
#pragma unroll
  for (int qt = 0; qt < 2; ++qt) {
    int grow = g0 - 1 + qt * 16 + l15;          // score row -> global row (halo)
    grow = grow < 0 ? 0 : (grow > SEQ - 1 ? SEQ - 1 : grow);  // clamped rows are zeroed at conv
    const float* qp = Q + ((size_t)(b * SEQ + grow)) * DIMD + hi * 8;
#pragma unroll
    for (int ks = 0; ks < 4; ++ks) {
      float4 x = *(const float4*)(qp + ks * 32);
      float4 y = *(const float4*)(qp + ks * 32 + 4);
      bf16x8 f;
      f[0] = (short)f2bf(x.x); f[1] = (short)f2bf(x.y);
      f[2] = (short)f2bf(x.z); f[3] = (short)f2bf(x.w);
      f[4] = (short)f2bf(y.x); f[5] = (short)f2bf(y.y);
      f[6] = (short)f2bf(y.z); f[7] = (short)f2bf(y.w);
      aq[qt][ks] = f;
    }
  }

  // =================== phase 1: QK^T -> score LDS (bf16, swizzled) ===================
  const unsigned short* KbB = Kb + (size_t)b * SEQ * DIMD;
  {  // prologue: stage chunk 0 (64 keys, 16 KiB)
#pragma unroll
    for (int s = 0; s < 2; ++s) {
      int sl = w * 2 + s;
      int o = sl * 1024 + lane * 16;
      int krow = o >> 8;
      int cc = ((o >> 4) & 15) ^ (krow & 7);      // pre-swizzled source chunk
      gll16(KbB + (size_t)krow * DIMD + cc * 8, buf0 + sl * 1024);
    }
  }
  __syncthreads();

  const int kw = w >> 1, qt1 = w & 1;   // wave grid: 2 (q) x 4 (key)
  for (int c = 0; c < 32; ++c) {
    if (c + 1 < 32) {
      char* nb = (c & 1) ? buf0 : buf1;
#pragma unroll
      for (int s = 0; s < 2; ++s) {
        int sl = w * 2 + s;
        int o = sl * 1024 + lane * 16;
        int krow = o >> 8;
        int cc = ((o >> 4) & 15) ^ (krow & 7);
        gll16(KbB + (size_t)((c + 1) * 64 + krow) * DIMD + cc * 8, nb + sl * 1024);
      }
    }
    const char* cbuf = (c & 1) ? buf1 : buf0;
    f32x4 acc = {0.f, 0.f, 0.f, 0.f};
    const int krl = kw * 16 + l15;
    const int ksw = (krl & 7) << 4;
#pragma unroll
    for (int ks = 0; ks < 4; ++ks) {
      bf16x8 bf = *(const bf16x8*)(cbuf + krl * 256 + ((ks * 64 + hi * 16) ^ ksw));
      acc = __builtin_amdgcn_mfma_f32_16x16x32_bf16(aq[qt1][ks], bf, acc, 0, 0, 0);
    }
    const int col2 = (c * 64 + kw * 16 + l15) * 2;
#pragma unroll
    for (int r = 0; r < 4; ++r) {
      int row = qt1 * 16 + hi * 4 + r;            // C/D: row=(lane>>4)*4+reg, col=lane&15
      if (row < SROWS) {
        *(unsigned short*)(smem + row * SC_STRIDE + (col2 ^ ((row & 7) << 4))) =
            f2bf(acc[r] * SCALE);
      }
    }
    __syncthreads();
  }

  // =================== phase 2: conv + mask + softmax ===================
  const int nrows = (SEQ - g0) < QT_OUT ? (SEQ - g0) : QT_OUT;
  float* attnB = attn + (size_t)b * SEQ * SEQ;

  for (int sp = 0; sp < 4; ++sp) {
    const int i = sp * 8 + w;                  // local output row; one wave per row
    const bool act = (i < nrows);
    float p[32];
    float inv = 0.f;
    if (act) {
      const int g = g0 + i;
      const bool vtop = (g > 0);
      const bool vbot = (g + 1 < SEQ);
#pragma unroll
      for (int jb = 0; jb < 8; ++jb) {
        const int colb = jb * 256 + lane * 4;
        float M[4][3], Lv[3], Rv[3];
#pragma unroll
        for (int r = 0; r < 3; ++r) {
          const int row = i + r;               // score rows i..i+2 (global g-1..g+1)
          const bool v = (r == 1) || ((r == 0) ? vtop : vbot);
          if (v) {
            const int rs = row * SC_STRIDE, sw = (row & 7) << 4;
            ushort4 mm = *(const ushort4*)(smem + rs + ((colb * 2) ^ sw));
            M[0][r] = bf2f(mm.x); M[1][r] = bf2f(mm.y);
            M[2][r] = bf2f(mm.z); M[3][r] = bf2f(mm.w);
            Lv[r] = (colb > 0)
                        ? bf2f(*(const unsigned short*)(smem + rs + (((colb - 1) * 2) ^ sw)))
                        : 0.f;
            Rv[r] = (colb + 4 < SEQ)
                        ? bf2f(*(const unsigned short*)(smem + rs + (((colb + 4) * 2) ^ sw)))
                        : 0.f;
          } else {
            M[0][r] = 0.f; M[1][r] = 0.f; M[2][r] = 0.f; M[3][r] = 0.f;
            Lv[r] = 0.f; Rv[r] = 0.f;
          }
        }
#pragma unroll
        for (int c = 0; c < 4; ++c) {
          float cv = 0.f;
#pragma unroll
          for (int r = 0; r < 3; ++r) {
            const float lft = (c == 0) ? Lv[r] : M[c - 1][r];
            const float rgt = (c == 3) ? Rv[r] : M[c + 1][r];
            cv += w9[r * 3 + 0] * lft + w9[r * 3 + 1] * M[c][r] + w9[r * 3 + 2] * rgt;
          }
          const float val = M[c][1] + fmaxf(cv + bias, 0.f);
          p[jb * 4 + c] = ((mb >> (jb * 4 + c)) & 1u) ? val : -1e9f;
        }
      }
      float mx = p[0];
#pragma unroll
      for (int k = 1; k < 32; ++k) mx = fmaxf(mx, p[k]);
#pragma unroll
      for (int o = 1; o < 64; o <<= 1) mx = fmaxf(mx, __shfl_xor(mx, o, 64));
      float Z = 0.f;
#pragma unroll
      for (int k = 0; k < 32; ++k) { p[k] = exp2f((p[k] - mx) * L2E); Z += p[k]; }
#pragma unroll
      for (int o = 1; o < 64; o <<= 1) Z += __shfl_xor(Z, o, 64);
      inv = 1.0f / Z;
      float* arow = attnB + (size_t)g * SEQ;
#pragma unroll
      for (int jb = 0; jb < 8; ++jb) {
        float4 o4 = make_float4(p[jb * 4 + 0] * inv, p[jb * 4 + 1] * inv,
                                p[jb * 4 + 2] * inv, p[jb * 4 + 3] * inv);
        *(float4*)(arow + jb * 256 + lane * 4) = o4;
      }
    }
    __syncthreads();   // all reads of this sub-phase done before clobbering
    if (act) {
      const int rs = i * SC_STRIDE, sw = (i & 7) << 4;
#pragma unroll
      for (int jb = 0; jb < 8; ++jb) {
        ushort4 h;
        h.x = f2bf(p[jb * 4 + 0] * inv); h.y = f2bf(p[jb * 4 + 1] * inv);
        h.z = f2bf(p[jb * 4 + 2] * inv); h.w = f2bf(p[jb * 4 + 3] * inv);
        *(ushort4*)(smem + rs + ((jb * 512 + lane * 8) ^ sw)) = h;
      }
    }
    __syncthreads();
  }

  // =================== phase 3: PV MFMA ===================
  const unsigned short* VtB = Vt + (size_t)b * DIMD * SEQ;
  f32x4 acc0 = {0.f, 0.f, 0.f, 0.f}, acc1 = {0.f, 0.f, 0.f, 0.f};
  const int qbase = (w & 1) * 14;   // overlapping q-tiles 0..15 and 14..29
  const int dp = w >> 1;            // d-tile pair
  {
#pragma unroll
    for (int s = 0; s < 2; ++s) {
      int sl = w * 2 + s;
      int o = sl * 1024 + lane * 16;
      int d = o >> 7;
      int cc = ((o >> 4) & 7) ^ (d & 7);
      gll16(VtB + (size_t)d * SEQ + cc * 8, buf0 + sl * 1024);
    }
  }
  __syncthreads();

  const int arw = qbase + l15;
  const int asw = (arw & 7) << 4;
  for (int c = 0; c < 32; ++c) {
    if (c + 1 < 32) {
      char* nb = (c & 1) ? buf0 : buf1;
#pragma unroll
      for (int s = 0; s < 2; ++s) {
        int sl = w * 2 + s;
        int o = sl * 1024 + lane * 16;
        int d = o >> 7;
        int cc = ((o >> 4) & 7) ^ (d & 7);
        gll16(VtB + (size_t)d * SEQ + (c + 1) * 64 + cc * 8, nb + sl * 1024);
      }
    }
    const char* cbuf = (c & 1) ? buf1 : buf0;
#pragma unroll
    for (int ks = 0; ks < 2; ++ks) {
      bf16x8 af = *(const bf16x8*)(smem + arw * SC_STRIDE +
                                   ((c * 128 + ks * 64 + hi * 16) ^ asw));
#pragma unroll
      for (int dd = 0; dd < 2; ++dd) {
        const int d = (dp * 2 + dd) * 16 + l15;
        bf16x8 bf = *(const bf16x8*)(cbuf + d * 128 +
                                     ((ks * 64 + hi * 16) ^ ((d & 7) << 4)));
        if (dd == 0) acc0 = __builtin_amdgcn_mfma_f32_16x16x32_bf16(af, bf, acc0, 0, 0, 0);
        else         acc1 = __builtin_amdgcn_mfma_f32_16x16x32_bf16(af, bf, acc1, 0, 0, 0);
      }
    }
    __syncthreads();
  }

  // epilogue: context write (each tile keeps its first 14 rows)
#pragma unroll
  for (int dd = 0; dd < 2; ++dd) {
    const int col = (dp * 2 + dd) * 16 + l15;
    const f32x4 a = dd ? acc1 : acc0;
#pragma unroll
    for (int r = 0; r < 4; ++r) {
      const int row = hi * 4 + r;
      if (row <= 13) {
        const int g = g0 + qbase + row;
        if (g < SEQ) ctx[((size_t)(b * SEQ + g)) * DIMD + col] = a[r];
      }
    }
  }
}

// ---------------- launch ----------------
extern "C" void kernel_launch(void* const* d_in, const int* in_sizes, int n_in,
                              void* d_out, int out_size, void* d_ws, size_t ws_size,
                              hipStream_t stream) {
  const float* Q  = (const float*)d_in[0];
  const float* K  = (const float*)d_in[1];
  const float* V  = (const float*)d_in[2];
  const int* msk  = (const int*)d_in[3];
  const float* cw = (const float*)d_in[4];
  const float* cb = (const float*)d_in[5];
  float* ctx  = (float*)d_out;
  float* attn = ctx + (size_t)B_BATCH * SEQ * DIMD;      // outputs concatenated: (context, atten)
  // workspace: Kb (bf16, 8 MiB) + Vt (bf16, 8 MiB) = 16 MiB
  unsigned short* Kb = (unsigned short*)d_ws;
  unsigned short* Vt = Kb + (size_t)B_BATCH * SEQ * DIMD;

  cvt_bf16<<<2048, 256, 0, stream>>>(K, Kb);
  transpose_v<<<B_BATCH * 64, 256, 0, stream>>>(V, Vt);
  fused_attn<<<B_BATCH * TILES_PB, 512, 0, stream>>>(Q, Kb, Vt, msk, cw, cb, ctx, attn);
}